// Round 6
// baseline (433.731 us; speedup 1.0000x reference)
//
#include <hip/hip_runtime.h>
#include <hip/hip_bf16.h>
#include <string.h>

// PerformerAttention: out = (relu(xWq^T+bq) @ [relu(xWk^T+bk)^T @ (xWv^T+bv)]_per-head) Wo^T + bo
// B=4 S=8192 E=768 H=12 Dh=64.
// Round 3: kv_partial2 (8x8-per-lane VALU, barrier-free waves, transposed P[e][d]) +
// qkv_mfma (MFMA NT GEMM vs bf16 KVt). GEMMs unchanged (m97 structure).
//
// Workspace layout (bytes):
//   0        : Wq_b  (768*768*2 = 1179648)
//   1179648  : Wk_b
//   2359296  : Wv_b
//   3538944  : Wo_b
//   4718592  : Qb   [32768,768] bf16 relu'd   (50331648)
//   55050240 : Kb   [32768,768] bf16 relu'd   (later reused as QKVb)
//   105381888: Vb   [32768,768] bf16
//   155713536: P    partial KVt [48*16][64e*64d] f32 (12582912)
//   168296448: KVt  [48][64e*64d] bf16 (393216)

#define H_  12
#define DH  64
#define E_  768
#define S_  8192
#define B_  4

typedef unsigned short u16;
typedef __attribute__((ext_vector_type(4))) float f32x4;
typedef __attribute__((ext_vector_type(4))) u16   u16x4;
typedef __attribute__((ext_vector_type(8))) u16   u16x8;
typedef __attribute__((ext_vector_type(8))) short s16x8;

static __device__ __forceinline__ u16 f2bf(float f) {
    __hip_bfloat16 h = __float2bfloat16(f);   // RNE via v_cvt hardware
    u16 r; __builtin_memcpy(&r, &h, 2); return r;
}
static __device__ __forceinline__ float bf2f(u16 u) {
    unsigned int i = ((unsigned int)u) << 16;
    float f; __builtin_memcpy(&f, &i, 4); return f;
}

// async global->LDS, 16 B per lane; LDS dest is wave-uniform base + lane*16 (HW scatter).
static __device__ __forceinline__ void gload16(const void* g, void* lds) {
    __builtin_amdgcn_global_load_lds(
        (const __attribute__((address_space(1))) unsigned int*)(uintptr_t)g,
        (__attribute__((address_space(3))) unsigned int*)(uintptr_t)lds,
        16, 0, 0);
}

// ---------------- weight f32 -> bf16 (tiny) ----------------
__global__ __launch_bounds__(256) void wconv(const float* __restrict__ in,
                                             u16* __restrict__ out, int n) {
    int i = (blockIdx.x * 256 + threadIdx.x) * 4;
    if (i + 3 < n) {
        f32x4 v = *(const f32x4*)&in[i];
        u16x4 o;
        o[0] = f2bf(v[0]); o[1] = f2bf(v[1]); o[2] = f2bf(v[2]); o[3] = f2bf(v[3]);
        *(u16x4*)&out[i] = o;
    }
}

// ---------------- input f32 -> bf16, 8 elems/thread ----------------
__global__ __launch_bounds__(256) void xconv(const float* __restrict__ in,
                                             u16* __restrict__ out) {
    long i = ((long)blockIdx.x * 256 + threadIdx.x) * 8;
    f32x4 a = *(const f32x4*)&in[i];
    f32x4 b = *(const f32x4*)&in[i + 4];
    u16x8 o;
    o[0] = f2bf(a[0]); o[1] = f2bf(a[1]); o[2] = f2bf(a[2]); o[3] = f2bf(a[3]);
    o[4] = f2bf(b[0]); o[5] = f2bf(b[1]); o[6] = f2bf(b[2]); o[7] = f2bf(b[3]);
    *(u16x8*)&out[i] = o;
}

// ---------------- bf16 MFMA GEMM, NT, m97 structure ----------------
template<int RELU, int OUT_F32>
__global__ __launch_bounds__(256) void gemm_bt(const u16*  __restrict__ A,
                                               const u16*  __restrict__ Bw,
                                               const float* __restrict__ bias,
                                               void* __restrict__ Cp, int K) {
    __shared__ u16 As[128 * 32];
    __shared__ u16 Bs[128 * 32];
    const int  t    = threadIdx.x;
    const int  lane = t & 63;
    const int  wave = t >> 6;
    const long m0   = (long)blockIdx.x * 128;
    const long n0   = (long)blockIdx.y * 128;
    const int  wr   = (wave >> 1) * 64;
    const int  wc   = (wave & 1) * 64;
    const int  N    = gridDim.y * 128;

    const int ob0 = wave * 1024;
    const int ob1 = 4096 + wave * 1024;
    const int ol0 = ob0 + lane * 16;
    const int ol1 = ob1 + lane * 16;
    const int r0  = ol0 >> 6, c0 = (ol0 & 63) >> 1;
    const int r1  = ol1 >> 6, c1 = (ol1 & 63) >> 1;
    const u16* gA0 = A  + (m0 + r0) * (long)K + c0;
    const u16* gA1 = A  + (m0 + r1) * (long)K + c1;
    const u16* gB0 = Bw + (n0 + r0) * (long)K + c0;
    const u16* gB1 = Bw + (n0 + r1) * (long)K + c1;
    char* lA = (char*)As;
    char* lB = (char*)Bs;

    f32x4 acc[4][4] = {};

    for (int k0 = 0; k0 < K; k0 += 32) {
        gload16(gA0 + k0, lA + ob0);
        gload16(gA1 + k0, lA + ob1);
        gload16(gB0 + k0, lB + ob0);
        gload16(gB1 + k0, lB + ob1);
        __syncthreads();

        s16x8 af[4], bfr[4];
        #pragma unroll
        for (int mi = 0; mi < 4; ++mi)
            af[mi] = *(const s16x8*)&As[(wr + mi * 16 + (lane & 15)) * 32 + (lane >> 4) * 8];
        #pragma unroll
        for (int ni = 0; ni < 4; ++ni)
            bfr[ni] = *(const s16x8*)&Bs[(wc + ni * 16 + (lane & 15)) * 32 + (lane >> 4) * 8];
        #pragma unroll
        for (int mi = 0; mi < 4; ++mi)
            #pragma unroll
            for (int ni = 0; ni < 4; ++ni)
                acc[mi][ni] = __builtin_amdgcn_mfma_f32_16x16x32_bf16(af[mi], bfr[ni], acc[mi][ni], 0, 0, 0);
        __syncthreads();
    }

    const int cc = lane & 15;
    const int cr = (lane >> 4) * 4;
    float bv[4];
    #pragma unroll
    for (int ni = 0; ni < 4; ++ni) bv[ni] = bias[n0 + wc + ni * 16 + cc];
    #pragma unroll
    for (int mi = 0; mi < 4; ++mi) {
        #pragma unroll
        for (int r = 0; r < 4; ++r) {
            long gm = m0 + wr + mi * 16 + cr + r;
            #pragma unroll
            for (int ni = 0; ni < 4; ++ni) {
                long gn = n0 + wc + ni * 16 + cc;
                float v = acc[mi][ni][r] + bv[ni];
                if (RELU) v = fmaxf(v, 0.0f);
                if (OUT_F32) ((float*)Cp)[gm * N + gn] = v;
                else         ((u16*)Cp)[gm * N + gn]   = f2bf(v);
            }
        }
    }
}

// ---------------- KV partial v2: P[bhc][e][d] = sum_{l in chunk} V[l,e]*K[l,d] ----------------
// 4 independent waves per block (own LDS quarter, no per-step barriers); each lane owns an
// 8x8 (e x d) sub-block: per l, 4 ds_read_b128 feed 64 FMA. Block tree-reduce at the end.
__global__ __launch_bounds__(256) void kv_partial2(const u16* __restrict__ Kb,
                                                   const u16* __restrict__ Vb,
                                                   float* __restrict__ P) {
    __shared__ float sbuf[8192];   // per-wave: Kf[16][64] f32 + Vf[16][64] f32 (8 KB)
    const int bh = blockIdx.x, ch = blockIdx.y;
    const int b = bh / H_, h = bh - b * H_;
    const int t = threadIdx.x, lane = t & 63, wave = t >> 6;
    float* Kf = sbuf + wave * 2048;
    float* Vf = Kf + 1024;
    const long base = ((long)b * S_) * E_ + h * DH;
    const int eB = (lane >> 3) * 8;   // row-block (e)
    const int dB = (lane & 7) * 8;    // col-block (d)

    f32x4 acc[8][2] = {};             // acc[i][j]: P[eB+i][dB + j*4 ..]

    const int l0w = ch * 512 + wave * 128;
    for (int ss = 0; ss < 8; ++ss) {
        const int l0 = l0w + ss * 16;
        #pragma unroll
        for (int half = 0; half < 2; ++half) {
            int u  = lane + half * 64;     // 8-elem unit
            int lr = u >> 3, c0 = (u & 7) * 8;
            long g = base + (long)(l0 + lr) * E_ + c0;
            u16x8 kk = *(const u16x8*)&Kb[g];
            u16x8 vv = *(const u16x8*)&Vb[g];
            f32x4 k0, k1, v0, v1;
            #pragma unroll
            for (int j = 0; j < 4; ++j) {
                k0[j] = bf2f(kk[j]); k1[j] = bf2f(kk[j + 4]);
                v0[j] = bf2f(vv[j]); v1[j] = bf2f(vv[j + 4]);
            }
            *(f32x4*)&Kf[lr * 64 + c0]     = k0;
            *(f32x4*)&Kf[lr * 64 + c0 + 4] = k1;
            *(f32x4*)&Vf[lr * 64 + c0]     = v0;
            *(f32x4*)&Vf[lr * 64 + c0 + 4] = v1;
        }
        // same-wave LDS RAW/WAR: DS ops are in-order per wave; compiler inserts lgkmcnt
        #pragma unroll
        for (int l = 0; l < 16; ++l) {
            f32x4 e0 = *(const f32x4*)&Vf[l * 64 + eB];
            f32x4 e1 = *(const f32x4*)&Vf[l * 64 + eB + 4];
            f32x4 d0 = *(const f32x4*)&Kf[l * 64 + dB];
            f32x4 d1 = *(const f32x4*)&Kf[l * 64 + dB + 4];
            #pragma unroll
            for (int i = 0; i < 4; ++i) {
                acc[i][0]     += e0[i] * d0;  acc[i][1]     += e0[i] * d1;
                acc[i + 4][0] += e1[i] * d0;  acc[i + 4][1] += e1[i] * d1;
            }
        }
    }

    // cross-wave tree reduce: (2,3) -> (0,1); 1 -> 0; wave 0 writes P
    __syncthreads();
    if (wave >= 2) {
        float* r = sbuf + (wave - 2) * 4096;
        #pragma unroll
        for (int i = 0; i < 8; ++i) {
            *(f32x4*)&r[(eB + i) * 64 + dB]     = acc[i][0];
            *(f32x4*)&r[(eB + i) * 64 + dB + 4] = acc[i][1];
        }
    }
    __syncthreads();
    if (wave < 2) {
        const float* r = sbuf + wave * 4096;
        #pragma unroll
        for (int i = 0; i < 8; ++i) {
            acc[i][0] += *(const f32x4*)&r[(eB + i) * 64 + dB];
            acc[i][1] += *(const f32x4*)&r[(eB + i) * 64 + dB + 4];
        }
    }
    __syncthreads();
    if (wave == 1) {
        #pragma unroll
        for (int i = 0; i < 8; ++i) {
            *(f32x4*)&sbuf[(eB + i) * 64 + dB]     = acc[i][0];
            *(f32x4*)&sbuf[(eB + i) * 64 + dB + 4] = acc[i][1];
        }
    }
    __syncthreads();
    if (wave == 0) {
        float* Pp = &P[((long)(bh * 16 + ch)) * 4096];
        #pragma unroll
        for (int i = 0; i < 8; ++i) {
            f32x4 s0 = acc[i][0] + *(const f32x4*)&sbuf[(eB + i) * 64 + dB];
            f32x4 s1 = acc[i][1] + *(const f32x4*)&sbuf[(eB + i) * 64 + dB + 4];
            *(f32x4*)&Pp[(eB + i) * 64 + dB]     = s0;
            *(f32x4*)&Pp[(eB + i) * 64 + dB + 4] = s1;
        }
    }
}

// ---------------- KV reduce: sum 16 chunks, write bf16 KVt[bh][e*64+d] ----------------
__global__ __launch_bounds__(256) void kv_reduce(const float* __restrict__ P,
                                                 u16* __restrict__ KVt) {
    const int bh = blockIdx.x, t = threadIdx.x;
    #pragma unroll
    for (int k = 0; k < 4; ++k) {
        int i = t * 4 + k * 1024;
        f32x4 s = {};
        for (int c = 0; c < 16; ++c) s += *(const f32x4*)&P[((long)(bh * 16 + c)) * 4096 + i];
        u16x4 o;
        #pragma unroll
        for (int j = 0; j < 4; ++j) o[j] = f2bf(s[j]);
        *(u16x4*)&KVt[(long)bh * 4096 + i] = o;
    }
}

// ---------------- QKV via MFMA: C[l][e] = sum_d Q[l][d] * KVt[e][d] ----------------
// grid (32 rowblk, 12 h, 4 b); 256 thr = 4 waves; wave w: rows [w*64, +64) x all 64 e.
__global__ __launch_bounds__(256) void qkv_mfma(const u16* __restrict__ Qb,
                                                const u16* __restrict__ KVt,
                                                u16* __restrict__ Ob) {
    __shared__ u16 Qs[256 * 64];   // 32 KB
    __shared__ u16 Ks[64 * 64];    // 8 KB, KVt tile [e][d]
    const int t = threadIdx.x, lane = t & 63, wave = t >> 6;
    const int h = blockIdx.y, b = blockIdx.z;
    const long r0 = (long)b * S_ + (long)blockIdx.x * 256;

    {
        char* lq = (char*)Qs;
        #pragma unroll
        for (int j = 0; j < 8; ++j) {
            int ob = (wave * 8 + j) * 1024;
            int ol = ob + lane * 16;
            int row = ol >> 7, col = (ol & 127) >> 1;
            gload16(&Qb[(r0 + row) * E_ + h * DH + col], lq + ob);
        }
        char* lk = (char*)Ks;
        #pragma unroll
        for (int j = 0; j < 2; ++j) {
            int ob = (wave * 2 + j) * 1024;
            int ol = ob + lane * 16;
            int row = ol >> 7, col = (ol & 127) >> 1;
            gload16(&KVt[((long)(b * H_ + h)) * 4096 + row * 64 + col], lk + ob);
        }
    }
    __syncthreads();

    f32x4 acc[4][4] = {};
    #pragma unroll
    for (int kk = 0; kk < 2; ++kk) {
        s16x8 af[4], bfr[4];
        #pragma unroll
        for (int mi = 0; mi < 4; ++mi)
            af[mi] = *(const s16x8*)&Qs[(wave * 64 + mi * 16 + (lane & 15)) * 64 + kk * 32 + (lane >> 4) * 8];
        #pragma unroll
        for (int ni = 0; ni < 4; ++ni)
            bfr[ni] = *(const s16x8*)&Ks[(ni * 16 + (lane & 15)) * 64 + kk * 32 + (lane >> 4) * 8];
        #pragma unroll
        for (int mi = 0; mi < 4; ++mi)
            #pragma unroll
            for (int ni = 0; ni < 4; ++ni)
                acc[mi][ni] = __builtin_amdgcn_mfma_f32_16x16x32_bf16(af[mi], bfr[ni], acc[mi][ni], 0, 0, 0);
    }

    const int cc = lane & 15, cr = (lane >> 4) * 4;
    #pragma unroll
    for (int mi = 0; mi < 4; ++mi) {
        #pragma unroll
        for (int r = 0; r < 4; ++r) {
            long gm = r0 + wave * 64 + mi * 16 + cr + r;
            #pragma unroll
            for (int ni = 0; ni < 4; ++ni)
                Ob[gm * E_ + h * DH + ni * 16 + cc] = f2bf(acc[mi][ni][r]);
        }
    }
}

extern "C" void kernel_launch(void* const* d_in, const int* in_sizes, int n_in,
                              void* d_out, int out_size, void* d_ws, size_t ws_size,
                              hipStream_t stream) {
    const float* q  = (const float*)d_in[0];
    const float* k  = (const float*)d_in[1];
    const float* v  = (const float*)d_in[2];
    const float* Wq = (const float*)d_in[3];
    const float* bq = (const float*)d_in[4];
    const float* Wk = (const float*)d_in[5];
    const float* bk = (const float*)d_in[6];
    const float* Wv = (const float*)d_in[7];
    const float* bv = (const float*)d_in[8];
    const float* Wo = (const float*)d_in[9];
    const float* bo = (const float*)d_in[10];
    float* out = (float*)d_out;

    char* ws = (char*)d_ws;
    u16*   Wq_b = (u16*)(ws);
    u16*   Wk_b = (u16*)(ws + 1179648L);
    u16*   Wv_b = (u16*)(ws + 2359296L);
    u16*   Wo_b = (u16*)(ws + 3538944L);
    u16*   Qb   = (u16*)(ws + 4718592L);
    u16*   Kb   = (u16*)(ws + 55050240L);
    u16*   Vb   = (u16*)(ws + 105381888L);
    float* P    = (float*)(ws + 155713536L);
    u16*   KVt  = (u16*)(ws + 168296448L);
    u16*   QKVb = Kb;            // Kb dead after kv_partial2 — reuse
    u16*   xb   = (u16*)d_out;   // d_out as conversion scratch; overwritten by final GEMM

    dim3 blk(256);
    wconv<<<576, blk, 0, stream>>>(Wq, Wq_b, 589824);
    wconv<<<576, blk, 0, stream>>>(Wk, Wk_b, 589824);
    wconv<<<576, blk, 0, stream>>>(Wv, Wv_b, 589824);
    wconv<<<576, blk, 0, stream>>>(Wo, Wo_b, 589824);

    dim3 g1(256, 6);  // M=32768/128, N=768/128
    xconv<<<12288, blk, 0, stream>>>(q, xb);
    gemm_bt<1, 0><<<g1, blk, 0, stream>>>(xb, Wq_b, bq, Qb, 768);
    xconv<<<12288, blk, 0, stream>>>(k, xb);
    gemm_bt<1, 0><<<g1, blk, 0, stream>>>(xb, Wk_b, bk, Kb, 768);
    xconv<<<12288, blk, 0, stream>>>(v, xb);
    gemm_bt<0, 0><<<g1, blk, 0, stream>>>(xb, Wv_b, bv, Vb, 768);

    kv_partial2<<<dim3(48, 16), blk, 0, stream>>>(Kb, Vb, P);
    kv_reduce<<<48, blk, 0, stream>>>(P, KVt);
    qkv_mfma<<<dim3(32, 12, 4), blk, 0, stream>>>(Qb, KVt, QKVb);

    gemm_bt<0, 1><<<g1, blk, 0, stream>>>(QKVb, Wo_b, bo, out, 768);
}

// Round 7
// 415.334 us; speedup vs baseline: 1.0443x; 1.0443x over previous
//
#include <hip/hip_runtime.h>
#include <hip/hip_bf16.h>
#include <string.h>

// PerformerAttention: out = (relu(xWq^T+bq) @ [relu(xWk^T+bk)^T @ (xWv^T+bv)]_per-head) Wo^T + bo
// B=4 S=8192 E=768 H=12 Dh=64.
// Round 7: gemm_bt2 — BK=64, double-buffered LDS, single barrier/K-step with
// next-tile prefetch (minimum-T3 recipe), XOR bank-conflict swizzle (G4 r268 form,
// rule-#21: linear gload_lds dest + pre-swizzled global source + swizzled ds_read),
// setprio around MFMA. Tail kernels unchanged (near HBM floor).
//
// Workspace layout (bytes):
//   0        : Wq_b  (768*768*2 = 1179648)
//   1179648  : Wk_b
//   2359296  : Wv_b
//   3538944  : Wo_b
//   4718592  : Qb   [32768,768] bf16 relu'd   (50331648)
//   55050240 : Kb   [32768,768] bf16 relu'd   (later reused as QKVb)
//   105381888: Vb   [32768,768] bf16
//   155713536: P    partial KVt [48*16][64e*64d] f32 (12582912)
//   168296448: KVt  [48][64e*64d] bf16 (393216)

#define H_  12
#define DH  64
#define E_  768
#define S_  8192
#define B_  4

typedef unsigned short u16;
typedef __attribute__((ext_vector_type(4))) float f32x4;
typedef __attribute__((ext_vector_type(4))) u16   u16x4;
typedef __attribute__((ext_vector_type(8))) u16   u16x8;
typedef __attribute__((ext_vector_type(8))) short s16x8;

static __device__ __forceinline__ u16 f2bf(float f) {
    __hip_bfloat16 h = __float2bfloat16(f);   // RNE via v_cvt hardware
    u16 r; __builtin_memcpy(&r, &h, 2); return r;
}
static __device__ __forceinline__ float bf2f(u16 u) {
    unsigned int i = ((unsigned int)u) << 16;
    float f; __builtin_memcpy(&f, &i, 4); return f;
}

// async global->LDS, 16 B per lane; LDS dest is wave-uniform base + lane*16 (HW scatter).
static __device__ __forceinline__ void gload16(const void* g, void* lds) {
    __builtin_amdgcn_global_load_lds(
        (const __attribute__((address_space(1))) unsigned int*)(uintptr_t)g,
        (__attribute__((address_space(3))) unsigned int*)(uintptr_t)lds,
        16, 0, 0);
}

// ---------------- weight f32 -> bf16 (tiny) ----------------
__global__ __launch_bounds__(256) void wconv(const float* __restrict__ in,
                                             u16* __restrict__ out, int n) {
    int i = (blockIdx.x * 256 + threadIdx.x) * 4;
    if (i + 3 < n) {
        f32x4 v = *(const f32x4*)&in[i];
        u16x4 o;
        o[0] = f2bf(v[0]); o[1] = f2bf(v[1]); o[2] = f2bf(v[2]); o[3] = f2bf(v[3]);
        *(u16x4*)&out[i] = o;
    }
}

// ---------------- input f32 -> bf16, 8 elems/thread ----------------
__global__ __launch_bounds__(256) void xconv(const float* __restrict__ in,
                                             u16* __restrict__ out) {
    long i = ((long)blockIdx.x * 256 + threadIdx.x) * 8;
    f32x4 a = *(const f32x4*)&in[i];
    f32x4 b = *(const f32x4*)&in[i + 4];
    u16x8 o;
    o[0] = f2bf(a[0]); o[1] = f2bf(a[1]); o[2] = f2bf(a[2]); o[3] = f2bf(a[3]);
    o[4] = f2bf(b[0]); o[5] = f2bf(b[1]); o[6] = f2bf(b[2]); o[7] = f2bf(b[3]);
    *(u16x8*)&out[i] = o;
}

// ---------------- bf16 MFMA GEMM, NT: BK=64, dbuf, swizzled LDS ----------------
// BM=BN=128, 256 threads = 4 waves (2x2), each wave 64x64 = 4x4 16x16x32 frags, 2 kk.
// LDS tile [128 rows][64 cols] bf16 = 128 B/row. Swizzle: phys = log ^ ((log_row&7)<<4)
// (XOR into colbyte bits 4-6). Writes: gload_lds linear dest, source pre-unswizzled.
// Reads: frag addr = row*128 + ((kk*64 + (lane>>4)*16) ^ ((lane&7)<<4)); row&7==lane&7.
template<int RELU, int OUT_F32>
__global__ __launch_bounds__(256) void gemm_bt2(const u16*  __restrict__ A,
                                                const u16*  __restrict__ Bw,
                                                const float* __restrict__ bias,
                                                void* __restrict__ Cp, int K) {
    __shared__ u16 As[2][128 * 64];
    __shared__ u16 Bs[2][128 * 64];
    const int  t    = threadIdx.x;
    const int  lane = t & 63;
    const int  wave = t >> 6;
    const long m0   = (long)blockIdx.x * 128;
    const long n0   = (long)blockIdx.y * 128;
    const int  wr   = (wave >> 1) * 64;
    const int  wc   = (wave & 1) * 64;
    const int  N    = gridDim.y * 128;

    // staging: 16 chunks of 1 KB per tile; wave w owns chunks [4w, 4w+4).
    // phys offset o = chunk*1024 + lane*16; logical lo = o ^ (((o>>7)&7)<<4);
    // global src = base + (tile_row)*K + colbyte/2.
    const u16* srcA[4];
    const u16* srcB[4];
    int dstc[4];
    #pragma unroll
    for (int c = 0; c < 4; ++c) {
        int o   = (wave * 4 + c) * 1024 + lane * 16;
        int lo  = o ^ (((o >> 7) & 7) << 4);
        int row = lo >> 7, colb = lo & 127;
        dstc[c] = (wave * 4 + c) * 1024;
        srcA[c] = A  + (m0 + row) * (long)K + (colb >> 1);
        srcB[c] = Bw + (n0 + row) * (long)K + (colb >> 1);
    }

    // swizzled read offsets
    const int rbase = (lane & 15) * 128;
    const int rx    = (lane & 7) << 4;
    const int ccb   = (lane >> 4) * 16;
    const int koff0 = ccb ^ rx;
    const int koff1 = (64 + ccb) ^ rx;

    f32x4 acc[4][4] = {};

    // prologue: stage K-tile 0 into buf 0
    {
        char* la = (char*)&As[0][0];
        char* lb = (char*)&Bs[0][0];
        #pragma unroll
        for (int c = 0; c < 4; ++c) gload16(srcA[c], la + dstc[c]);
        #pragma unroll
        for (int c = 0; c < 4; ++c) gload16(srcB[c], lb + dstc[c]);
    }
    __syncthreads();   // vmcnt(0) drain + barrier

    const int nk = K >> 6;   // K/64
    for (int kt = 0; kt < nk; ++kt) {
        // prefetch next K-tile into the other buffer (reads of it completed
        // before the PREVIOUS __syncthreads)
        if (kt + 1 < nk) {
            const int k0 = (kt + 1) << 6;
            char* la = (char*)&As[(kt + 1) & 1][0];
            char* lb = (char*)&Bs[(kt + 1) & 1][0];
            #pragma unroll
            for (int c = 0; c < 4; ++c) gload16(srcA[c] + k0, la + dstc[c]);
            #pragma unroll
            for (int c = 0; c < 4; ++c) gload16(srcB[c] + k0, lb + dstc[c]);
        }

        const char* as = (const char*)&As[kt & 1][0];
        const char* bs = (const char*)&Bs[kt & 1][0];
        s16x8 af[4][2], bf[4][2];
        #pragma unroll
        for (int mi = 0; mi < 4; ++mi) {
            const int rb = (wr + mi * 16) * 128 + rbase;
            af[mi][0] = *(const s16x8*)(as + rb + koff0);
            af[mi][1] = *(const s16x8*)(as + rb + koff1);
        }
        #pragma unroll
        for (int ni = 0; ni < 4; ++ni) {
            const int rb = (wc + ni * 16) * 128 + rbase;
            bf[ni][0] = *(const s16x8*)(bs + rb + koff0);
            bf[ni][1] = *(const s16x8*)(bs + rb + koff1);
        }

        __builtin_amdgcn_s_setprio(1);
        #pragma unroll
        for (int kk = 0; kk < 2; ++kk)
            #pragma unroll
            for (int mi = 0; mi < 4; ++mi)
                #pragma unroll
                for (int ni = 0; ni < 4; ++ni)
                    acc[mi][ni] = __builtin_amdgcn_mfma_f32_16x16x32_bf16(
                        af[mi][kk], bf[ni][kk], acc[mi][ni], 0, 0, 0);
        __builtin_amdgcn_s_setprio(0);

        __syncthreads();   // drains this iter's prefetch (vmcnt 0) + LDS WAR
    }

    // ---- epilogue: C/D layout col = lane&15, row = (lane>>4)*4 + r ----
    const int cc = lane & 15;
    const int cr = (lane >> 4) * 4;
    float bv[4];
    #pragma unroll
    for (int ni = 0; ni < 4; ++ni) bv[ni] = bias[n0 + wc + ni * 16 + cc];
    #pragma unroll
    for (int mi = 0; mi < 4; ++mi) {
        #pragma unroll
        for (int r = 0; r < 4; ++r) {
            long gm = m0 + wr + mi * 16 + cr + r;
            #pragma unroll
            for (int ni = 0; ni < 4; ++ni) {
                long gn = n0 + wc + ni * 16 + cc;
                float v = acc[mi][ni][r] + bv[ni];
                if (RELU) v = fmaxf(v, 0.0f);
                if (OUT_F32) ((float*)Cp)[gm * N + gn] = v;
                else         ((u16*)Cp)[gm * N + gn]   = f2bf(v);
            }
        }
    }
}

// ---------------- KV partial v2: P[bhc][e][d] = sum_{l in chunk} V[l,e]*K[l,d] ----------------
__global__ __launch_bounds__(256) void kv_partial2(const u16* __restrict__ Kb,
                                                   const u16* __restrict__ Vb,
                                                   float* __restrict__ P) {
    __shared__ float sbuf[8192];   // per-wave: Kf[16][64] f32 + Vf[16][64] f32 (8 KB)
    const int bh = blockIdx.x, ch = blockIdx.y;
    const int b = bh / H_, h = bh - b * H_;
    const int t = threadIdx.x, lane = t & 63, wave = t >> 6;
    float* Kf = sbuf + wave * 2048;
    float* Vf = Kf + 1024;
    const long base = ((long)b * S_) * E_ + h * DH;
    const int eB = (lane >> 3) * 8;
    const int dB = (lane & 7) * 8;

    f32x4 acc[8][2] = {};

    const int l0w = ch * 512 + wave * 128;
    for (int ss = 0; ss < 8; ++ss) {
        const int l0 = l0w + ss * 16;
        #pragma unroll
        for (int half = 0; half < 2; ++half) {
            int u  = lane + half * 64;
            int lr = u >> 3, c0 = (u & 7) * 8;
            long g = base + (long)(l0 + lr) * E_ + c0;
            u16x8 kk = *(const u16x8*)&Kb[g];
            u16x8 vv = *(const u16x8*)&Vb[g];
            f32x4 k0, k1, v0, v1;
            #pragma unroll
            for (int j = 0; j < 4; ++j) {
                k0[j] = bf2f(kk[j]); k1[j] = bf2f(kk[j + 4]);
                v0[j] = bf2f(vv[j]); v1[j] = bf2f(vv[j + 4]);
            }
            *(f32x4*)&Kf[lr * 64 + c0]     = k0;
            *(f32x4*)&Kf[lr * 64 + c0 + 4] = k1;
            *(f32x4*)&Vf[lr * 64 + c0]     = v0;
            *(f32x4*)&Vf[lr * 64 + c0 + 4] = v1;
        }
        #pragma unroll
        for (int l = 0; l < 16; ++l) {
            f32x4 e0 = *(const f32x4*)&Vf[l * 64 + eB];
            f32x4 e1 = *(const f32x4*)&Vf[l * 64 + eB + 4];
            f32x4 d0 = *(const f32x4*)&Kf[l * 64 + dB];
            f32x4 d1 = *(const f32x4*)&Kf[l * 64 + dB + 4];
            #pragma unroll
            for (int i = 0; i < 4; ++i) {
                acc[i][0]     += e0[i] * d0;  acc[i][1]     += e0[i] * d1;
                acc[i + 4][0] += e1[i] * d0;  acc[i + 4][1] += e1[i] * d1;
            }
        }
    }

    __syncthreads();
    if (wave >= 2) {
        float* r = sbuf + (wave - 2) * 4096;
        #pragma unroll
        for (int i = 0; i < 8; ++i) {
            *(f32x4*)&r[(eB + i) * 64 + dB]     = acc[i][0];
            *(f32x4*)&r[(eB + i) * 64 + dB + 4] = acc[i][1];
        }
    }
    __syncthreads();
    if (wave < 2) {
        const float* r = sbuf + wave * 4096;
        #pragma unroll
        for (int i = 0; i < 8; ++i) {
            acc[i][0] += *(const f32x4*)&r[(eB + i) * 64 + dB];
            acc[i][1] += *(const f32x4*)&r[(eB + i) * 64 + dB + 4];
        }
    }
    __syncthreads();
    if (wave == 1) {
        #pragma unroll
        for (int i = 0; i < 8; ++i) {
            *(f32x4*)&sbuf[(eB + i) * 64 + dB]     = acc[i][0];
            *(f32x4*)&sbuf[(eB + i) * 64 + dB + 4] = acc[i][1];
        }
    }
    __syncthreads();
    if (wave == 0) {
        float* Pp = &P[((long)(bh * 16 + ch)) * 4096];
        #pragma unroll
        for (int i = 0; i < 8; ++i) {
            f32x4 s0 = acc[i][0] + *(const f32x4*)&sbuf[(eB + i) * 64 + dB];
            f32x4 s1 = acc[i][1] + *(const f32x4*)&sbuf[(eB + i) * 64 + dB + 4];
            *(f32x4*)&Pp[(eB + i) * 64 + dB]     = s0;
            *(f32x4*)&Pp[(eB + i) * 64 + dB + 4] = s1;
        }
    }
}

// ---------------- KV reduce: sum 16 chunks, write bf16 KVt[bh][e*64+d] ----------------
__global__ __launch_bounds__(256) void kv_reduce(const float* __restrict__ P,
                                                 u16* __restrict__ KVt) {
    const int bh = blockIdx.x, t = threadIdx.x;
    #pragma unroll
    for (int k = 0; k < 4; ++k) {
        int i = t * 4 + k * 1024;
        f32x4 s = {};
        for (int c = 0; c < 16; ++c) s += *(const f32x4*)&P[((long)(bh * 16 + c)) * 4096 + i];
        u16x4 o;
        #pragma unroll
        for (int j = 0; j < 4; ++j) o[j] = f2bf(s[j]);
        *(u16x4*)&KVt[(long)bh * 4096 + i] = o;
    }
}

// ---------------- QKV via MFMA: C[l][e] = sum_d Q[l][d] * KVt[e][d] ----------------
__global__ __launch_bounds__(256) void qkv_mfma(const u16* __restrict__ Qb,
                                                const u16* __restrict__ KVt,
                                                u16* __restrict__ Ob) {
    __shared__ u16 Qs[256 * 64];   // 32 KB
    __shared__ u16 Ks[64 * 64];    // 8 KB
    const int t = threadIdx.x, lane = t & 63, wave = t >> 6;
    const int h = blockIdx.y, b = blockIdx.z;
    const long r0 = (long)b * S_ + (long)blockIdx.x * 256;

    {
        char* lq = (char*)Qs;
        #pragma unroll
        for (int j = 0; j < 8; ++j) {
            int ob = (wave * 8 + j) * 1024;
            int ol = ob + lane * 16;
            int row = ol >> 7, col = (ol & 127) >> 1;
            gload16(&Qb[(r0 + row) * E_ + h * DH + col], lq + ob);
        }
        char* lk = (char*)Ks;
        #pragma unroll
        for (int j = 0; j < 2; ++j) {
            int ob = (wave * 2 + j) * 1024;
            int ol = ob + lane * 16;
            int row = ol >> 7, col = (ol & 127) >> 1;
            gload16(&KVt[((long)(b * H_ + h)) * 4096 + row * 64 + col], lk + ob);
        }
    }
    __syncthreads();

    f32x4 acc[4][4] = {};
    #pragma unroll
    for (int kk = 0; kk < 2; ++kk) {
        s16x8 af[4], bfr[4];
        #pragma unroll
        for (int mi = 0; mi < 4; ++mi)
            af[mi] = *(const s16x8*)&Qs[(wave * 64 + mi * 16 + (lane & 15)) * 64 + kk * 32 + (lane >> 4) * 8];
        #pragma unroll
        for (int ni = 0; ni < 4; ++ni)
            bfr[ni] = *(const s16x8*)&Ks[(ni * 16 + (lane & 15)) * 64 + kk * 32 + (lane >> 4) * 8];
        #pragma unroll
        for (int mi = 0; mi < 4; ++mi)
            #pragma unroll
            for (int ni = 0; ni < 4; ++ni)
                acc[mi][ni] = __builtin_amdgcn_mfma_f32_16x16x32_bf16(af[mi], bfr[ni], acc[mi][ni], 0, 0, 0);
    }

    const int cc = lane & 15, cr = (lane >> 4) * 4;
    #pragma unroll
    for (int mi = 0; mi < 4; ++mi) {
        #pragma unroll
        for (int r = 0; r < 4; ++r) {
            long gm = r0 + wave * 64 + mi * 16 + cr + r;
            #pragma unroll
            for (int ni = 0; ni < 4; ++ni)
                Ob[gm * E_ + h * DH + ni * 16 + cc] = f2bf(acc[mi][ni][r]);
        }
    }
}

extern "C" void kernel_launch(void* const* d_in, const int* in_sizes, int n_in,
                              void* d_out, int out_size, void* d_ws, size_t ws_size,
                              hipStream_t stream) {
    const float* q  = (const float*)d_in[0];
    const float* k  = (const float*)d_in[1];
    const float* v  = (const float*)d_in[2];
    const float* Wq = (const float*)d_in[3];
    const float* bq = (const float*)d_in[4];
    const float* Wk = (const float*)d_in[5];
    const float* bk = (const float*)d_in[6];
    const float* Wv = (const float*)d_in[7];
    const float* bv = (const float*)d_in[8];
    const float* Wo = (const float*)d_in[9];
    const float* bo = (const float*)d_in[10];
    float* out = (float*)d_out;

    char* ws = (char*)d_ws;
    u16*   Wq_b = (u16*)(ws);
    u16*   Wk_b = (u16*)(ws + 1179648L);
    u16*   Wv_b = (u16*)(ws + 2359296L);
    u16*   Wo_b = (u16*)(ws + 3538944L);
    u16*   Qb   = (u16*)(ws + 4718592L);
    u16*   Kb   = (u16*)(ws + 55050240L);
    u16*   Vb   = (u16*)(ws + 105381888L);
    float* P    = (float*)(ws + 155713536L);
    u16*   KVt  = (u16*)(ws + 168296448L);
    u16*   QKVb = Kb;            // Kb dead after kv_partial2 — reuse
    u16*   xb   = (u16*)d_out;   // d_out as conversion scratch; overwritten by final GEMM

    dim3 blk(256);
    wconv<<<576, blk, 0, stream>>>(Wq, Wq_b, 589824);
    wconv<<<576, blk, 0, stream>>>(Wk, Wk_b, 589824);
    wconv<<<576, blk, 0, stream>>>(Wv, Wv_b, 589824);
    wconv<<<576, blk, 0, stream>>>(Wo, Wo_b, 589824);

    dim3 g1(256, 6);  // M=32768/128, N=768/128
    xconv<<<12288, blk, 0, stream>>>(q, xb);
    gemm_bt2<1, 0><<<g1, blk, 0, stream>>>(xb, Wq_b, bq, Qb, 768);
    xconv<<<12288, blk, 0, stream>>>(k, xb);
    gemm_bt2<1, 0><<<g1, blk, 0, stream>>>(xb, Wk_b, bk, Kb, 768);
    xconv<<<12288, blk, 0, stream>>>(v, xb);
    gemm_bt2<0, 0><<<g1, blk, 0, stream>>>(xb, Wv_b, bv, Vb, 768);

    kv_partial2<<<dim3(48, 16), blk, 0, stream>>>(Kb, Vb, P);
    kv_reduce<<<48, blk, 0, stream>>>(P, KVt);
    qkv_mfma<<<dim3(32, 12, 4), blk, 0, stream>>>(Qb, KVt, QKVb);

    gemm_bt2<0, 1><<<g1, blk, 0, stream>>>(QKVb, Wo_b, bo, out, 768);
}